// Round 1
// baseline (2666.033 us; speedup 1.0000x reference)
//
#include <hip/hip_runtime.h>
#include <math.h>

// ---------------- workspace layout (float offsets) ----------------
// Wt  : [1280][6272]  transposed W                     8,028,160
// h   : [64][64][64][64] conv1 output                 16,777,216
// tmp : [64][64][28][28] primary conv output           3,211,264
// ut  : [64][8][6272] squashed capsule inputs          3,211,264
// s   : [64][10][16]                                      10,240
// v0  : [64][10][16]                                      10,240
// v1  : [64][10][16]                                      10,240
#define WT_OFF   0ULL
#define H_OFF    8028160ULL
#define TMP_OFF  24805376ULL
#define UT_OFF   28016640ULL
#define S_OFF    31227904ULL
#define V0_OFF   31238144ULL
#define V1_OFF   31248384ULL

// ---------------- W transpose: W[n][r] -> Wt[r][n], n=6272, r=1280 ----------------
__global__ __launch_bounds__(256) void transpose_w_kernel(const float* __restrict__ W,
                                                          float* __restrict__ Wt) {
    __shared__ float tile[32][33];
    int tn = blockIdx.x * 32;   // n tile base (196 tiles, exact)
    int tr = blockIdx.y * 32;   // r tile base (40 tiles, exact)
    int tx = threadIdx.x, ty = threadIdx.y;
    #pragma unroll
    for (int k = 0; k < 4; ++k) {
        int nl = ty + k * 8;
        tile[nl][tx] = W[(size_t)(tn + nl) * 1280 + tr + tx];
    }
    __syncthreads();
    #pragma unroll
    for (int k = 0; k < 4; ++k) {
        int rl = ty + k * 8;
        Wt[(size_t)(tr + rl) * 6272 + tn + tx] = tile[tx][rl];
    }
}

// ---------------- conv1: 1->64ch, k5, pad2, stride1, +bias, relu ----------------
__global__ __launch_bounds__(256) void conv1_kernel(const float* __restrict__ x,
                                                    const float* __restrict__ w,
                                                    const float* __restrict__ bias,
                                                    float* __restrict__ h) {
    int idx = blockIdx.x * 256 + threadIdx.x;      // 16,777,216 total
    int px = idx & 63, py = (idx >> 6) & 63, c = (idx >> 12) & 63, b = idx >> 18;
    const float* xb = x + (size_t)b * 4096;
    const float* wc = w + c * 25;
    float acc = bias[c];
    #pragma unroll
    for (int ky = 0; ky < 5; ++ky) {
        int iy = py + ky - 2;
        if (iy < 0 || iy > 63) continue;
        #pragma unroll
        for (int kx = 0; kx < 5; ++kx) {
            int ix = px + kx - 2;
            if (ix < 0 || ix > 63) continue;
            acc = fmaf(xb[iy * 64 + ix], wc[ky * 5 + kx], acc);
        }
    }
    h[idx] = fmaxf(acc, 0.f);
}

// ---------------- primary caps conv: 64->64ch, k9, stride2, VALID, +bias ----------------
// thread computes 4 consecutive x outputs for one (b,c,oy)
__global__ __launch_bounds__(256) void conv2_kernel(const float* __restrict__ h,
                                                    const float* __restrict__ pw,
                                                    const float* __restrict__ pb,
                                                    float* __restrict__ tmp) {
    int idx = blockIdx.x * 256 + threadIdx.x;      // 802,816 total
    int xg = idx % 7;
    int t = idx / 7;
    int oy = t % 28; t /= 28;
    int c = t & 63;  int b = t >> 6;
    float bv = pb[c];
    float a0 = bv, a1 = bv, a2 = bv, a3 = bv;
    const float* hb = h + (size_t)b * 64 * 4096;
    const float* wc = pw + (size_t)c * 64 * 81;
    for (int ic = 0; ic < 64; ++ic) {
        const float* hc = hb + ic * 4096;
        const float* wic = wc + ic * 81;
        #pragma unroll
        for (int ky = 0; ky < 9; ++ky) {
            const float* hrow = hc + (2 * oy + ky) * 64 + 8 * xg;  // ix base = 8*xg
            float r[15];
            #pragma unroll
            for (int q = 0; q < 15; ++q) r[q] = hrow[q];
            const float* wr = wic + ky * 9;
            #pragma unroll
            for (int kx = 0; kx < 9; ++kx) {
                float wv = wr[kx];
                a0 = fmaf(r[kx],     wv, a0);
                a1 = fmaf(r[kx + 2], wv, a1);
                a2 = fmaf(r[kx + 4], wv, a2);
                a3 = fmaf(r[kx + 6], wv, a3);
            }
        }
    }
    float* op = tmp + ((size_t)(b * 64 + c) * 28 + oy) * 28 + xg * 4;
    op[0] = a0; op[1] = a1; op[2] = a2; op[3] = a3;
}

// ---------------- squash u + transpose to ut[b][j][n] ----------------
__global__ __launch_bounds__(256) void squash_u_kernel(const float* __restrict__ tmp,
                                                       float* __restrict__ ut) {
    int idx = blockIdx.x * 256 + threadIdx.x;      // 401,408 total
    int n = idx % 6272;
    int b = idx / 6272;
    int caps = n / 784, p = n % 784;
    float v[8]; float msq = 0.f;
    #pragma unroll
    for (int j = 0; j < 8; ++j) {
        v[j] = tmp[(size_t)(b * 64 + caps * 8 + j) * 784 + p];
        msq = fmaf(v[j], v[j], msq);
    }
    float mag = sqrtf(msq + 1e-9f);
    float sc = msq / (1.f + msq) / (mag + 1e-9f);
    #pragma unroll
    for (int j = 0; j < 8; ++j) ut[((size_t)b * 8 + j) * 6272 + n] = v[j] * sc;
}

// ---------------- routing iteration ----------------
// ITER 0: c = 0.1 uniform.  ITER 1: logits = uh.v0.  ITER 2: logits = uh.(v0+v1).
// grid (49, 16), block 128 = 2 waves; wave handles 64 routes, lane carries 4 batches.
template<int ITER>
__global__ __launch_bounds__(128) void routing_kernel(const float* __restrict__ Wt,
                                                      const float* __restrict__ ut,
                                                      const float* __restrict__ v0,
                                                      const float* __restrict__ v1,
                                                      float* __restrict__ s) {
    __shared__ float vs[4][160];
    int tid = threadIdx.x;
    int b0 = blockIdx.y * 4;
    if (ITER >= 1) {
        for (int k = tid; k < 640; k += 128) {
            int bb = k / 160, oi = k % 160;
            float val = v0[(b0 + bb) * 160 + oi];
            if (ITER == 2) val += v1[(b0 + bb) * 160 + oi];
            vs[bb][oi] = val;
        }
        __syncthreads();
    }
    int wv = tid >> 6, lane = tid & 63;
    int chunk = blockIdx.x * 2 + wv;               // 0..97, exact
    int n = chunk * 64 + lane;

    float u[4][8];
    #pragma unroll
    for (int bb = 0; bb < 4; ++bb)
        #pragma unroll
        for (int j = 0; j < 8; ++j)
            u[bb][j] = ut[((size_t)(b0 + bb) * 8 + j) * 6272 + n];

    float c[4][10];
    if (ITER >= 1) {
        for (int o = 0; o < 10; ++o) {
            float l0 = 0.f, l1 = 0.f, l2 = 0.f, l3 = 0.f;
            for (int i = 0; i < 16; ++i) {
                float wr[8];
                #pragma unroll
                for (int j = 0; j < 8; ++j)
                    wr[j] = Wt[((size_t)((o * 16 + i) * 8 + j)) * 6272 + n];
                float uh;
                #pragma unroll
                for (int bb = 0; bb < 4; ++bb) {
                    uh = 0.f;
                    #pragma unroll
                    for (int j = 0; j < 8; ++j) uh = fmaf(wr[j], u[bb][j], uh);
                    float vv = vs[bb][o * 16 + i];
                    if (bb == 0) l0 = fmaf(uh, vv, l0);
                    else if (bb == 1) l1 = fmaf(uh, vv, l1);
                    else if (bb == 2) l2 = fmaf(uh, vv, l2);
                    else l3 = fmaf(uh, vv, l3);
                }
            }
            c[0][o] = l0; c[1][o] = l1; c[2][o] = l2; c[3][o] = l3;
        }
        #pragma unroll
        for (int bb = 0; bb < 4; ++bb) {
            float m = c[bb][0];
            #pragma unroll
            for (int o = 1; o < 10; ++o) m = fmaxf(m, c[bb][o]);
            float sum = 0.f;
            #pragma unroll
            for (int o = 0; o < 10; ++o) { c[bb][o] = expf(c[bb][o] - m); sum += c[bb][o]; }
            float inv = 1.f / sum;
            #pragma unroll
            for (int o = 0; o < 10; ++o) c[bb][o] *= inv;
        }
    }

    for (int o = 0; o < 10; ++o) {
        for (int i = 0; i < 16; ++i) {
            float wr[8];
            #pragma unroll
            for (int j = 0; j < 8; ++j)
                wr[j] = Wt[((size_t)((o * 16 + i) * 8 + j)) * 6272 + n];
            float val[4];
            #pragma unroll
            for (int bb = 0; bb < 4; ++bb) {
                float uh = 0.f;
                #pragma unroll
                for (int j = 0; j < 8; ++j) uh = fmaf(wr[j], u[bb][j], uh);
                val[bb] = (ITER == 0 ? 0.1f : c[bb][o]) * uh;
            }
            #pragma unroll
            for (int off = 32; off >= 1; off >>= 1) {
                #pragma unroll
                for (int bb = 0; bb < 4; ++bb)
                    val[bb] += __shfl_xor(val[bb], off);
            }
            if (lane == 0) {
                #pragma unroll
                for (int bb = 0; bb < 4; ++bb)
                    atomicAdd(&s[((b0 + bb) * 10 + o) * 16 + i], val[bb]);
            }
        }
    }
}

// ---------------- squash s -> v (640 vectors of 16) ----------------
__global__ void squash_v_kernel(const float* __restrict__ s, float* __restrict__ v) {
    int t = threadIdx.x;
    if (t >= 640) return;
    const float* sp = s + t * 16;
    float val[16]; float msq = 0.f;
    #pragma unroll
    for (int i = 0; i < 16; ++i) { val[i] = sp[i]; msq = fmaf(val[i], val[i], msq); }
    float mag = sqrtf(msq + 1e-9f);
    float sc = msq / (1.f + msq) / (mag + 1e-9f);
    float* vp = v + t * 16;
    #pragma unroll
    for (int i = 0; i < 16; ++i) vp[i] = val[i] * sc;
}

extern "C" void kernel_launch(void* const* d_in, const int* in_sizes, int n_in,
                              void* d_out, int out_size, void* d_ws, size_t ws_size,
                              hipStream_t stream) {
    const float* x  = (const float*)d_in[0];
    const float* w1 = (const float*)d_in[1];
    const float* b1 = (const float*)d_in[2];
    const float* pw = (const float*)d_in[3];
    const float* pb = (const float*)d_in[4];
    const float* W  = (const float*)d_in[5];
    float* out = (float*)d_out;
    float* ws  = (float*)d_ws;

    float* Wt  = ws + WT_OFF;
    float* h   = ws + H_OFF;
    float* tmp = ws + TMP_OFF;
    float* ut  = ws + UT_OFF;
    float* s   = ws + S_OFF;
    float* v0  = ws + V0_OFF;
    float* v1  = ws + V1_OFF;

    transpose_w_kernel<<<dim3(196, 40), dim3(32, 8), 0, stream>>>(W, Wt);
    conv1_kernel<<<65536, 256, 0, stream>>>(x, w1, b1, h);
    conv2_kernel<<<3136, 256, 0, stream>>>(h, pw, pb, tmp);
    squash_u_kernel<<<1568, 256, 0, stream>>>(tmp, ut);

    hipMemsetAsync(s, 0, 10240 * sizeof(float), stream);
    routing_kernel<0><<<dim3(49, 16), 128, 0, stream>>>(Wt, ut, nullptr, nullptr, s);
    squash_v_kernel<<<1, 640, 0, stream>>>(s, v0);

    hipMemsetAsync(s, 0, 10240 * sizeof(float), stream);
    routing_kernel<1><<<dim3(49, 16), 128, 0, stream>>>(Wt, ut, v0, nullptr, s);
    squash_v_kernel<<<1, 640, 0, stream>>>(s, v1);

    hipMemsetAsync(s, 0, 10240 * sizeof(float), stream);
    routing_kernel<2><<<dim3(49, 16), 128, 0, stream>>>(Wt, ut, v0, v1, s);
    squash_v_kernel<<<1, 640, 0, stream>>>(s, out);
}

// Round 2
// 937.605 us; speedup vs baseline: 2.8434x; 2.8434x over previous
//
#include <hip/hip_runtime.h>
#include <math.h>

typedef unsigned short ushort_t;
typedef __attribute__((ext_vector_type(8))) short bf16x8;
typedef __attribute__((ext_vector_type(4))) float f32x4;
typedef __attribute__((ext_vector_type(8))) unsigned short us8;

typedef __attribute__((address_space(1))) unsigned int gu32;
typedef __attribute__((address_space(3))) unsigned int lu32;

__device__ __forceinline__ void gload16(const void* g, void* l) {
    __builtin_amdgcn_global_load_lds((const gu32*)g, (lu32*)l, 16, 0, 0);
}

__device__ __forceinline__ unsigned short f2bf(float f) {
    unsigned u = __float_as_uint(f);
    unsigned r = ((u >> 16) & 1u) + 0x7fffu;
    return (unsigned short)((u + r) >> 16);
}

// ---------------- workspace layout (float offsets) ----------------
#define WT_OFF   0ULL           // Wt  [1280][6272] f32         8,028,160
#define HB_OFF   8028160ULL     // hb  [64][64][64][64] bf16    (8,388,608 f)
#define WT2_OFF  16416768ULL    // wt2 [81][64][64] bf16        (165,888 f)
#define TMP_OFF  16582656ULL    // tmp [64][784][64] f32        3,211,264
#define UT_OFF   19793920ULL    // ut  [64][8][6272] f32        3,211,264
#define S_OFF    23005184ULL
#define V0_OFF   23015424ULL
#define V1_OFF   23025664ULL

// ---------------- W transpose: W[n][r] -> Wt[r][n], n=6272, r=1280 ----------------
__global__ __launch_bounds__(256) void transpose_w_kernel(const float* __restrict__ W,
                                                          float* __restrict__ Wt) {
    __shared__ float tile[32][33];
    int tn = blockIdx.x * 32;
    int tr = blockIdx.y * 32;
    int tx = threadIdx.x, ty = threadIdx.y;
    #pragma unroll
    for (int k = 0; k < 4; ++k) {
        int nl = ty + k * 8;
        tile[nl][tx] = W[(size_t)(tn + nl) * 1280 + tr + tx];
    }
    __syncthreads();
    #pragma unroll
    for (int k = 0; k < 4; ++k) {
        int rl = ty + k * 8;
        Wt[(size_t)(tr + rl) * 6272 + tn + tx] = tile[tx][rl];
    }
}

// ---------------- conv1: 1->64ch, k5, pad2, +bias, relu -> NHWC bf16 ----------------
// block.x over (b,y,x), blockIdx.y = channel-group of 8
__global__ __launch_bounds__(256) void conv1_nhwc_kernel(const float* __restrict__ x,
                                                         const float* __restrict__ w,
                                                         const float* __restrict__ bias,
                                                         ushort_t* __restrict__ hb) {
    int t = blockIdx.x * 256 + threadIdx.x;         // 262144 (b,y,x)
    int xx = t & 63, yy = (t >> 6) & 63, b = t >> 12;
    int cg = blockIdx.y;                            // 0..7
    const float* xb = x + (size_t)b * 4096;
    float xv[25];
    #pragma unroll
    for (int ky = 0; ky < 5; ++ky) {
        int iy = yy + ky - 2;
        #pragma unroll
        for (int kx = 0; kx < 5; ++kx) {
            int ix = xx + kx - 2;
            bool ok = (iy >= 0 && iy < 64 && ix >= 0 && ix < 64);
            xv[ky * 5 + kx] = ok ? xb[iy * 64 + ix] : 0.f;
        }
    }
    us8 o;
    #pragma unroll
    for (int cc = 0; cc < 8; ++cc) {
        int c = cg * 8 + cc;
        float acc = bias[c];
        const float* wc = w + c * 25;
        #pragma unroll
        for (int k = 0; k < 25; ++k) acc = fmaf(xv[k], wc[k], acc);
        o[cc] = f2bf(fmaxf(acc, 0.f));
    }
    *(us8*)&hb[(size_t)t * 64 + cg * 8] = o;
}

// ---------------- conv2 weight transform: pw[c][ic][9][9] f32 -> wt2[p][c][ic] bf16 --------
__global__ __launch_bounds__(256) void wt2_transform_kernel(const float* __restrict__ pw,
                                                            ushort_t* __restrict__ wt2) {
    int t = blockIdx.x * 256 + threadIdx.x;         // 331776
    int ic = t & 63, c = (t >> 6) & 63, p = t >> 12;
    wt2[t] = f2bf(pw[(size_t)(c * 64 + ic) * 81 + p]);
}

// ---------------- conv2 implicit-GEMM MFMA: 64->64, k9, s2, +bias ----------------
// M=50176 (b,oy,ox), N=64 (c), K = 81 taps x 64 ic.  Block: 64x64 tile, 4 waves.
__global__ __launch_bounds__(256) void conv2_mfma_kernel(const ushort_t* __restrict__ hb,
                                                         const ushort_t* __restrict__ wt2,
                                                         const float* __restrict__ pb,
                                                         float* __restrict__ tmp) {
    __shared__ ushort_t As[2][4096];   // [64 rows][64 ic], swizzled chunks
    __shared__ ushort_t Bs[2][4096];   // [64 c][64 ic], swizzled chunks

    int tid = threadIdx.x;
    int w = tid >> 6, lane = tid & 63;
    int m0 = blockIdx.x * 64;

    // ---- staging addresses (per lane): wave w stages rows w*16 + (lane>>3) and +8
    int srow = w * 16 + (lane >> 3);
    int srcchunk = (lane & 7) ^ ((lane >> 3) & 7);   // inverse XOR swizzle on source
    unsigned gbaseA[2];
    #pragma unroll
    for (int k = 0; k < 2; ++k) {
        int r = srow + k * 8;
        int m = m0 + r;
        int b = m / 784, pos = m % 784;
        int oy = pos / 28, ox = pos % 28;
        gbaseA[k] = ((unsigned)((b * 64 + 2 * oy) * 64 + 2 * ox)) * 64 + srcchunk * 8;
    }
    unsigned gbaseB[2] = { (unsigned)srow * 64 + srcchunk * 8,
                           (unsigned)(srow + 8) * 64 + srcchunk * 8 };

    // ---- fragment read offsets (elements), swizzled
    int fr = lane & 15, fq = lane >> 4;
    int rlow = fr & 7;
    int c0 = (fq ^ rlow) * 8;            // k-step 0 chunk
    int c1 = ((4 + fq) ^ rlow) * 8;      // k-step 1 chunk
    int rowA = w * 16 + fr;
    int offA0 = rowA * 64 + c0, offA1 = rowA * 64 + c1;
    int offB0[4], offB1[4];
    #pragma unroll
    for (int jf = 0; jf < 4; ++jf) {
        int rowB = jf * 16 + fr;
        offB0[jf] = rowB * 64 + c0;
        offB1[jf] = rowB * 64 + c1;
    }

    f32x4 acc[4] = {};

    // stage position p into buffer buf
    auto stage = [&](int p, int buf) {
        int ky = p / 9, kx = p % 9;
        unsigned koff = (unsigned)(ky * 4096 + kx * 64);
        unsigned boff = (unsigned)p * 4096;
        gload16(hb + gbaseA[0] + koff, &As[buf][w * 1024]);
        gload16(hb + gbaseA[1] + koff, &As[buf][w * 1024 + 512]);
        gload16(wt2 + boff + gbaseB[0], &Bs[buf][w * 1024]);
        gload16(wt2 + boff + gbaseB[1], &Bs[buf][w * 1024 + 512]);
    };

    stage(0, 0);
    __syncthreads();

    for (int p = 0; p < 81; ++p) {
        int cur = p & 1;
        const ushort_t* A = As[cur];
        const ushort_t* B = Bs[cur];
        bf16x8 a0 = *(const bf16x8*)&A[offA0];
        bf16x8 a1 = *(const bf16x8*)&A[offA1];
        bf16x8 b0[4], b1[4];
        #pragma unroll
        for (int jf = 0; jf < 4; ++jf) {
            b0[jf] = *(const bf16x8*)&B[offB0[jf]];
            b1[jf] = *(const bf16x8*)&B[offB1[jf]];
        }
        #pragma unroll
        for (int jf = 0; jf < 4; ++jf)
            acc[jf] = __builtin_amdgcn_mfma_f32_16x16x32_bf16(a0, b0[jf], acc[jf], 0, 0, 0);
        #pragma unroll
        for (int jf = 0; jf < 4; ++jf)
            acc[jf] = __builtin_amdgcn_mfma_f32_16x16x32_bf16(a1, b1[jf], acc[jf], 0, 0, 0);
        if (p < 80) stage(p + 1, cur ^ 1);
        __syncthreads();
    }

    // epilogue: + bias, write tmp[b][pos][c] f32
    #pragma unroll
    for (int jf = 0; jf < 4; ++jf) {
        int n = jf * 16 + fr;
        float bv = pb[n];
        #pragma unroll
        for (int reg = 0; reg < 4; ++reg) {
            int m = w * 16 + fq * 4 + reg;
            tmp[(size_t)(m0 + m) * 64 + n] = acc[jf][reg] + bv;
        }
    }
}

// ---------------- squash u + transpose to ut[b][j][n] ----------------
__global__ __launch_bounds__(256) void squash_u_kernel(const float* __restrict__ tmp,
                                                       float* __restrict__ ut) {
    int idx = blockIdx.x * 256 + threadIdx.x;      // 401,408
    int n = idx % 6272;
    int b = idx / 6272;
    int caps = n / 784, pos = n % 784;
    const float* tp = tmp + ((size_t)b * 784 + pos) * 64 + caps * 8;
    float v[8]; float msq = 0.f;
    #pragma unroll
    for (int j = 0; j < 8; ++j) { v[j] = tp[j]; msq = fmaf(v[j], v[j], msq); }
    float mag = sqrtf(msq + 1e-9f);
    float sc = msq / (1.f + msq) / (mag + 1e-9f);
    #pragma unroll
    for (int j = 0; j < 8; ++j) ut[((size_t)b * 8 + j) * 6272 + n] = v[j] * sc;
}

// ---------------- routing iteration ----------------
template<int ITER>
__global__ __launch_bounds__(128) void routing_kernel(const float* __restrict__ Wt,
                                                      const float* __restrict__ ut,
                                                      const float* __restrict__ v0,
                                                      const float* __restrict__ v1,
                                                      float* __restrict__ s) {
    __shared__ float vs[4][160];
    int tid = threadIdx.x;
    int b0 = blockIdx.y * 4;
    if (ITER >= 1) {
        for (int k = tid; k < 640; k += 128) {
            int bb = k / 160, oi = k % 160;
            float val = v0[(b0 + bb) * 160 + oi];
            if (ITER == 2) val += v1[(b0 + bb) * 160 + oi];
            vs[bb][oi] = val;
        }
        __syncthreads();
    }
    int wv = tid >> 6, lane = tid & 63;
    int chunk = blockIdx.x * 2 + wv;
    int n = chunk * 64 + lane;

    float u[4][8];
    #pragma unroll
    for (int bb = 0; bb < 4; ++bb)
        #pragma unroll
        for (int j = 0; j < 8; ++j)
            u[bb][j] = ut[((size_t)(b0 + bb) * 8 + j) * 6272 + n];

    float c[4][10];
    if (ITER >= 1) {
        for (int o = 0; o < 10; ++o) {
            float l0 = 0.f, l1 = 0.f, l2 = 0.f, l3 = 0.f;
            for (int i = 0; i < 16; ++i) {
                float wr[8];
                #pragma unroll
                for (int j = 0; j < 8; ++j)
                    wr[j] = Wt[((size_t)((o * 16 + i) * 8 + j)) * 6272 + n];
                float uh;
                #pragma unroll
                for (int bb = 0; bb < 4; ++bb) {
                    uh = 0.f;
                    #pragma unroll
                    for (int j = 0; j < 8; ++j) uh = fmaf(wr[j], u[bb][j], uh);
                    float vv = vs[bb][o * 16 + i];
                    if (bb == 0) l0 = fmaf(uh, vv, l0);
                    else if (bb == 1) l1 = fmaf(uh, vv, l1);
                    else if (bb == 2) l2 = fmaf(uh, vv, l2);
                    else l3 = fmaf(uh, vv, l3);
                }
            }
            c[0][o] = l0; c[1][o] = l1; c[2][o] = l2; c[3][o] = l3;
        }
        #pragma unroll
        for (int bb = 0; bb < 4; ++bb) {
            float m = c[bb][0];
            #pragma unroll
            for (int o = 1; o < 10; ++o) m = fmaxf(m, c[bb][o]);
            float sum = 0.f;
            #pragma unroll
            for (int o = 0; o < 10; ++o) { c[bb][o] = expf(c[bb][o] - m); sum += c[bb][o]; }
            float inv = 1.f / sum;
            #pragma unroll
            for (int o = 0; o < 10; ++o) c[bb][o] *= inv;
        }
    }

    for (int o = 0; o < 10; ++o) {
        for (int i = 0; i < 16; ++i) {
            float wr[8];
            #pragma unroll
            for (int j = 0; j < 8; ++j)
                wr[j] = Wt[((size_t)((o * 16 + i) * 8 + j)) * 6272 + n];
            float val[4];
            #pragma unroll
            for (int bb = 0; bb < 4; ++bb) {
                float uh = 0.f;
                #pragma unroll
                for (int j = 0; j < 8; ++j) uh = fmaf(wr[j], u[bb][j], uh);
                val[bb] = (ITER == 0 ? 0.1f : c[bb][o]) * uh;
            }
            #pragma unroll
            for (int off = 32; off >= 1; off >>= 1) {
                #pragma unroll
                for (int bb = 0; bb < 4; ++bb)
                    val[bb] += __shfl_xor(val[bb], off);
            }
            if (lane == 0) {
                #pragma unroll
                for (int bb = 0; bb < 4; ++bb)
                    atomicAdd(&s[((b0 + bb) * 10 + o) * 16 + i], val[bb]);
            }
        }
    }
}

// ---------------- squash s -> v ----------------
__global__ void squash_v_kernel(const float* __restrict__ s, float* __restrict__ v) {
    int t = threadIdx.x;
    if (t >= 640) return;
    const float* sp = s + t * 16;
    float val[16]; float msq = 0.f;
    #pragma unroll
    for (int i = 0; i < 16; ++i) { val[i] = sp[i]; msq = fmaf(val[i], val[i], msq); }
    float mag = sqrtf(msq + 1e-9f);
    float sc = msq / (1.f + msq) / (mag + 1e-9f);
    float* vp = v + t * 16;
    #pragma unroll
    for (int i = 0; i < 16; ++i) vp[i] = val[i] * sc;
}

extern "C" void kernel_launch(void* const* d_in, const int* in_sizes, int n_in,
                              void* d_out, int out_size, void* d_ws, size_t ws_size,
                              hipStream_t stream) {
    const float* x  = (const float*)d_in[0];
    const float* w1 = (const float*)d_in[1];
    const float* b1 = (const float*)d_in[2];
    const float* pw = (const float*)d_in[3];
    const float* pb = (const float*)d_in[4];
    const float* W  = (const float*)d_in[5];
    float* out = (float*)d_out;
    float* ws  = (float*)d_ws;

    float*    Wt  = ws + WT_OFF;
    ushort_t* hb  = (ushort_t*)(ws + HB_OFF);
    ushort_t* wt2 = (ushort_t*)(ws + WT2_OFF);
    float*    tmp = ws + TMP_OFF;
    float*    ut  = ws + UT_OFF;
    float*    s   = ws + S_OFF;
    float*    v0  = ws + V0_OFF;
    float*    v1  = ws + V1_OFF;

    transpose_w_kernel<<<dim3(196, 40), dim3(32, 8), 0, stream>>>(W, Wt);
    conv1_nhwc_kernel<<<dim3(1024, 8), 256, 0, stream>>>(x, w1, b1, hb);
    wt2_transform_kernel<<<1296, 256, 0, stream>>>(pw, wt2);
    conv2_mfma_kernel<<<784, 256, 0, stream>>>(hb, wt2, pb, tmp);
    squash_u_kernel<<<1568, 256, 0, stream>>>(tmp, ut);

    hipMemsetAsync(s, 0, 10240 * sizeof(float), stream);
    routing_kernel<0><<<dim3(49, 16), 128, 0, stream>>>(Wt, ut, nullptr, nullptr, s);
    squash_v_kernel<<<1, 640, 0, stream>>>(s, v0);

    hipMemsetAsync(s, 0, 10240 * sizeof(float), stream);
    routing_kernel<1><<<dim3(49, 16), 128, 0, stream>>>(Wt, ut, v0, nullptr, s);
    squash_v_kernel<<<1, 640, 0, stream>>>(s, v1);

    hipMemsetAsync(s, 0, 10240 * sizeof(float), stream);
    routing_kernel<2><<<dim3(49, 16), 128, 0, stream>>>(Wt, ut, v0, v1, s);
    squash_v_kernel<<<1, 640, 0, stream>>>(s, out);
}